// Round 8
// baseline (730.416 us; speedup 1.0000x reference)
//
#include <hip/hip_runtime.h>

#define NP   8192
#define BB   4
#define DIN  32
#define M0   32
#define M1   32
#define M2   64
#define CAP  80
#define CSTR 81            // candidate row stride (odd -> conflict-free)
#define KWV  16            // waves per knn block
#define SEG  (NP / KWV)    // 512 points per wave
#define CHN  4             // points per lane per chunk (2 chunks)

typedef float v2f __attribute__((ext_vector_type(2)));

__device__ __forceinline__ float lrelu(float x) { return fmaxf(x, 0.1f * x); }
__device__ __forceinline__ unsigned umin_(unsigned a, unsigned b) { return a < b ? a : b; }
__device__ __forceinline__ unsigned umax_(unsigned a, unsigned b) { return a > b ? a : b; }

// monotonic float->uint key (total order incl. negatives)
__device__ __forceinline__ unsigned fkey(float f) {
    unsigned b = __float_as_uint(f);
    return (b & 0x80000000u) ? ~b : (b | 0x80000000u);
}
__device__ __forceinline__ float funkey(unsigned k) {
    unsigned b = (k & 0x80000000u) ? (k & 0x7fffffffu) : ~k;
    return __uint_as_float(b);
}

// round-to-nearest-even f32 -> bf16 (as uint16 in low bits)
__device__ __forceinline__ unsigned bf16rn(float f) {
    unsigned u = __float_as_uint(f);
    unsigned r = (u >> 16) & 1u;
    return (u + 0x7fffu + r) >> 16;
}

// ---------------------------------------------------------------------------
// Kernel 1: pack pts (AoS float4) and feat = W0[:,3:] @ points stored as bf16
// pairs. Block = 4 waves over the same 64 points; wave w computes outs [8w,8w+8).
// ---------------------------------------------------------------------------
__global__ __launch_bounds__(256) void prep_kernel(
    const float* __restrict__ xyz, const float* __restrict__ points,
    const float* __restrict__ W0, float4* __restrict__ pts4,
    unsigned* __restrict__ featb)
{
    const int tid  = threadIdx.x;
    const int w    = __builtin_amdgcn_readfirstlane(tid >> 6);  // 0..3
    const int lane = tid & 63;
    const int t    = blockIdx.x * 64 + lane;     // point id, 512 blocks
    const int b    = t >> 13;
    const int n    = t & (NP - 1);

    if (w == 0) {
        const float* xb = xyz + (size_t)b * 3 * NP;
        float x = xb[n], y = xb[NP + n], z = xb[2 * NP + n];
        float s = x * x + y * y + z * z;
        pts4[t] = make_float4(x, y, z, s);
    }

    const float* pb = points + (size_t)b * DIN * NP + n;
    float p[DIN];
#pragma unroll
    for (int c = 0; c < DIN; ++c) p[c] = pb[c * NP];

    uint4 outv;
    unsigned* ov = (unsigned*)&outv;
#pragma unroll
    for (int r = 0; r < 4; ++r) {
        int oe = w * 8 + 2 * r;
        float a0 = 0.f, a1 = 0.f;
#pragma unroll
        for (int c = 0; c < DIN; ++c) {
            a0 = fmaf(W0[oe * 35 + 3 + c], p[c], a0);
            a1 = fmaf(W0[(oe + 1) * 35 + 3 + c], p[c], a1);
        }
        ov[r] = bf16rn(a0) | (bf16rn(a1) << 16);
    }
    *(uint4*)(featb + (size_t)t * 16 + w * 4) = outv;
}

// ---------------------------------------------------------------------------
// Kernel 2: exact 16-NN, lane = point, packed query pairs, CHUNKED to fit the
// 64-VGPR budget the compiler picks at this LDS/occupancy point (r6/r7 spilled).
// 16 waves/block, 64 queries. Each chunk: 4 points/lane in registers; loop all
// 32 query-pairs; pk_fma + pk_min; atomicMin class merge (class = lane).
// T[q] = 16th smallest of 64 class minima (>=16 distinct points <= T).
// Pass 2: same chunk structure, bit-identical packed recompute, append t<=T
// to cand[q*81+pos]; exact (t,idx)-lex top-16; overflow -> exact full scan.
// ---------------------------------------------------------------------------
__global__ __launch_bounds__(1024, 4) void knn_kernel(const float4* __restrict__ pts4,
                                                      int* __restrict__ idxout)
{
    __shared__ float    qx2[64], qy2[64], qz2[64];  // -2*coord per query
    __shared__ unsigned skey[64 * 65];              // 16.6 KB class-min keys
    __shared__ float    sT[64];
    __shared__ int      scnt[64];
    __shared__ float    cand_t[64 * CSTR];          // 20.7 KB
    __shared__ int      cand_i[64 * CSTR];          // 20.7 KB

    const int tid  = threadIdx.x;
    const int w    = __builtin_amdgcn_readfirstlane(tid >> 6);
    const int lane = tid & 63;
    const int blk  = blockIdx.x;           // 512 blocks
    const int b    = blk >> 7;
    const int n0   = (blk & 127) << 6;
    const int bn0  = b * NP;
    const float4* P = pts4 + bn0;

    for (int i = tid; i < 64 * 65; i += 1024) skey[i] = 0xFFFFFFFFu;
    if (tid < 64) {
        float4 q4 = P[n0 + tid];
        qx2[tid] = -2.f * q4.x; qy2[tid] = -2.f * q4.y; qz2[tid] = -2.f * q4.z;
        scnt[tid] = 0;
    }
    __syncthreads();

    const int base = w * SEG;

    // ---- pass 1: chunked (4 pts/lane), packed query pairs ----
#pragma unroll
    for (int ch = 0; ch < 2; ++ch) {
        float4 pt[CHN];
#pragma unroll
        for (int i = 0; i < CHN; ++i) pt[i] = P[base + (ch * CHN + i) * 64 + lane];
#pragma unroll
        for (int p = 0; p < 32; ++p) {
            v2f cx = *(const v2f*)&qx2[2 * p];
            v2f cy = *(const v2f*)&qy2[2 * p];
            v2f cz = *(const v2f*)&qz2[2 * p];
            v2f m2 = {1e30f, 1e30f};
#pragma unroll
            for (int i = 0; i < CHN; ++i) {
                v2f px = {pt[i].x, pt[i].x};
                v2f py = {pt[i].y, pt[i].y};
                v2f pz = {pt[i].z, pt[i].z};
                v2f pw = {pt[i].w, pt[i].w};
                v2f t = __builtin_elementwise_fma(cx, px,
                         __builtin_elementwise_fma(cy, py,
                          __builtin_elementwise_fma(cz, pz, pw)));
                m2 = __builtin_elementwise_min(m2, t);
            }
            atomicMin(&skey[(2 * p) * 65 + lane], fkey(m2.x));
            atomicMin(&skey[(2 * p + 1) * 65 + lane], fkey(m2.y));
        }
    }
    __syncthreads();

    // ---- threshold: 16th smallest of the 64 class minima (thread = query) ----
    if (tid < 64) {
        unsigned t16[16];
#pragma unroll
        for (int i = 0; i < 16; ++i) t16[i] = 0xFFFFFFFFu;
        for (int c = 0; c < 64; ++c) {
            unsigned d = skey[tid * 65 + c];
            if (d < t16[15]) {
                t16[15] = d;
#pragma unroll
                for (int i = 15; i > 0; --i) {
                    unsigned a = t16[i - 1], cc = t16[i];
                    t16[i - 1] = umin_(a, cc);
                    t16[i]     = umax_(a, cc);
                }
            }
        }
        sT[tid] = funkey(t16[15]);
    }
    __syncthreads();

    // ---- pass 2: chunked bit-identical recompute, append candidates ----
#pragma unroll
    for (int ch = 0; ch < 2; ++ch) {
        float4 pt[CHN];
#pragma unroll
        for (int i = 0; i < CHN; ++i) pt[i] = P[base + (ch * CHN + i) * 64 + lane];
#pragma unroll
        for (int p = 0; p < 32; ++p) {
            float T0 = sT[2 * p], T1 = sT[2 * p + 1];
            v2f cx = *(const v2f*)&qx2[2 * p];
            v2f cy = *(const v2f*)&qy2[2 * p];
            v2f cz = *(const v2f*)&qz2[2 * p];
#pragma unroll
            for (int i = 0; i < CHN; ++i) {
                v2f px = {pt[i].x, pt[i].x};
                v2f py = {pt[i].y, pt[i].y};
                v2f pz = {pt[i].z, pt[i].z};
                v2f pw = {pt[i].w, pt[i].w};
                v2f t = __builtin_elementwise_fma(cx, px,
                         __builtin_elementwise_fma(cy, py,
                          __builtin_elementwise_fma(cz, pz, pw)));
                int j = base + (ch * CHN + i) * 64 + lane;
                if (t.x <= T0) {
                    int pos = atomicAdd(&scnt[2 * p], 1);
                    if (pos < CAP) { cand_t[(2 * p) * CSTR + pos] = t.x; cand_i[(2 * p) * CSTR + pos] = j; }
                }
                if (t.y <= T1) {
                    int pos = atomicAdd(&scnt[2 * p + 1], 1);
                    if (pos < CAP) { cand_t[(2 * p + 1) * CSTR + pos] = t.y; cand_i[(2 * p + 1) * CSTR + pos] = j; }
                }
            }
        }
    }
    __syncthreads();

    // ---- exact selection among candidates (thread = query) ----
    if (tid < 64) {
        int cnt = scnt[tid];
        int* outp = idxout + ((bn0 + n0 + tid) << 4);
        float bd[16]; int bi[16];
#pragma unroll
        for (int i = 0; i < 16; ++i) { bd[i] = 3e38f; bi[i] = 0; }
        if (cnt <= CAP) {
            for (int pos = 0; pos < cnt; ++pos) {
                float d = cand_t[tid * CSTR + pos];
                int   j = cand_i[tid * CSTR + pos];
                if ((d < bd[15]) || (d == bd[15] && j < bi[15])) {
                    bd[15] = d; bi[15] = j;
#pragma unroll
                    for (int i = 15; i > 0; --i) {
                        bool sw = (bd[i] < bd[i - 1]) || (bd[i] == bd[i - 1] && bi[i] < bi[i - 1]);
                        float td = bd[i - 1]; int tj = bi[i - 1];
                        bd[i - 1] = sw ? bd[i] : td;  bi[i - 1] = sw ? bi[i] : tj;
                        bd[i]     = sw ? td : bd[i];  bi[i]     = sw ? tj : bi[i];
                    }
                }
            }
        } else {
            // overflow fallback (exact, never expected): identical metric form
            float cx = qx2[tid], cy = qy2[tid], cz = qz2[tid];
            for (int j = 0; j < NP; ++j) {
                float4 p = P[j];
                float d = fmaf(cx, p.x, fmaf(cy, p.y, fmaf(cz, p.z, p.w)));
                if ((d < bd[15]) || (d == bd[15] && j < bi[15])) {
                    bd[15] = d; bi[15] = j;
#pragma unroll
                    for (int i = 15; i > 0; --i) {
                        bool sw = (bd[i] < bd[i - 1]) || (bd[i] == bd[i - 1] && bi[i] < bi[i - 1]);
                        float td = bd[i - 1]; int tj = bi[i - 1];
                        bd[i - 1] = sw ? bd[i] : td;  bi[i - 1] = sw ? bi[i] : tj;
                        bd[i]     = sw ? td : bd[i];  bi[i]     = sw ? tj : bi[i];
                    }
                }
            }
        }
#pragma unroll
        for (int i = 0; i < 16; ++i) outp[i] = bi[i];
    }
}

// ---------------------------------------------------------------------------
// Kernel 3: gather + conv0/1/2 + max over K. One thread per (n,k) column,
// 256-thread blocks (16 n x 16 k), 2048 blocks. feat gathered as bf16.
// k-max via shfl_xor width 16.
// ---------------------------------------------------------------------------
__global__ __launch_bounds__(256, 4) void conv_kernel(
    const float4* __restrict__ pts4, const unsigned* __restrict__ featb,
    const int* __restrict__ idx,
    const float* __restrict__ W0, const float* __restrict__ W1, const float* __restrict__ W2,
    float* __restrict__ out)
{
    __shared__ float so[M2][17];
    const int tid = threadIdx.x;
    const int k   = tid & 15;
    const int nl  = tid >> 4;              // 0..15
    const int blk = blockIdx.x;            // 2048 blocks
    const int b   = blk >> 9;              // 512 blocks per batch
    const int n0  = (blk & 511) << 4;
    const int n   = n0 + nl;
    const int bn  = b * NP + n;
    const int j   = idx[(bn << 4) + k];
    const int bj  = b * NP + j;

    const float4 pc = pts4[bn];
    const float4 pj = pts4[bj];
    const float rx = pj.x - pc.x, ry = pj.y - pc.y, rz = pj.z - pc.z;

    const uint4* fj = (const uint4*)(featb + (size_t)bj * 16);

    float x0[M0];
#pragma unroll
    for (int g = 0; g < 4; ++g) {
        uint4 u = fj[g];
        const unsigned* uv = (const unsigned*)&u;
#pragma unroll
        for (int r = 0; r < 4; ++r) {
            int o = g * 8 + 2 * r;
            float fe  = __uint_as_float(uv[r] << 16);
            float fo_ = __uint_as_float(uv[r] & 0xffff0000u);
            x0[o]     = lrelu(fmaf(W0[o * 35], rx, fmaf(W0[o * 35 + 1], ry, fmaf(W0[o * 35 + 2], rz, fe))));
            x0[o + 1] = lrelu(fmaf(W0[(o + 1) * 35], rx, fmaf(W0[(o + 1) * 35 + 1], ry, fmaf(W0[(o + 1) * 35 + 2], rz, fo_))));
        }
    }

    float x1[M1];
#pragma unroll
    for (int o = 0; o < M1; ++o) {
        float acc = 0.f;
#pragma unroll
        for (int c = 0; c < M0; ++c) acc = fmaf(W1[o * 32 + c], x0[c], acc);
        x1[o] = lrelu(acc);
    }

#pragma unroll
    for (int o = 0; o < M2; ++o) {
        float acc = 0.f;
#pragma unroll
        for (int c = 0; c < M1; ++c) acc = fmaf(W2[o * 32 + c], x1[c], acc);
        float v = lrelu(acc);
        v = fmaxf(v, __shfl_xor(v, 1, 16));
        v = fmaxf(v, __shfl_xor(v, 2, 16));
        v = fmaxf(v, __shfl_xor(v, 4, 16));
        v = fmaxf(v, __shfl_xor(v, 8, 16));
        if (k == (o & 15)) so[o][nl] = v;
    }
    __syncthreads();
    {
        int o = tid >> 2;                 // 0..63
        int col = (tid & 3) << 2;         // 0,4,8,12
        float4 v = make_float4(so[o][col], so[o][col + 1], so[o][col + 2], so[o][col + 3]);
        *(float4*)(out + ((size_t)(b * M2 + o)) * NP + n0 + col) = v;
    }
}

// ---------------------------------------------------------------------------
extern "C" void kernel_launch(void* const* d_in, const int* in_sizes, int n_in,
                              void* d_out, int out_size, void* d_ws, size_t ws_size,
                              hipStream_t stream)
{
    const float* xyz    = (const float*)d_in[0];
    const float* points = (const float*)d_in[1];
    const float* W0     = (const float*)d_in[2];
    const float* W1     = (const float*)d_in[3];
    const float* W2     = (const float*)d_in[4];
    float* out = (float*)d_out;

    char* ws = (char*)d_ws;
    float4*   pts4  = (float4*)ws;                       // 512 KB
    unsigned* featb = (unsigned*)(ws + 0x100000);        // 2 MB
    int*      idx   = (int*)(ws + 0x300000);             // 2 MB

    prep_kernel<<<BB * NP / 64, 256,  0, stream>>>(xyz, points, W0, pts4, featb);
    knn_kernel <<<BB * NP / 64, 1024, 0, stream>>>(pts4, idx);
    conv_kernel<<<BB * NP / 16, 256,  0, stream>>>(pts4, featb, idx, W0, W1, W2, out);
}

// Round 9
// 272.207 us; speedup vs baseline: 2.6833x; 2.6833x over previous
//
#include <hip/hip_runtime.h>

#define NP   8192
#define BB   4
#define DIN  32
#define M0   32
#define M1   32
#define M2   64
#define CAP  80
#define CSTR 81            // candidate row stride (odd -> conflict-free)
#define KWV  16            // waves per knn block
#define SEG  (NP / KWV)    // 512 points per wave
#define PPL  8             // points per lane

typedef float v2f __attribute__((ext_vector_type(2)));

__device__ __forceinline__ float lrelu(float x) { return fmaxf(x, 0.1f * x); }
__device__ __forceinline__ unsigned umin_(unsigned a, unsigned b) { return a < b ? a : b; }
__device__ __forceinline__ unsigned umax_(unsigned a, unsigned b) { return a > b ? a : b; }

// monotonic float->uint key (total order incl. negatives)
__device__ __forceinline__ unsigned fkey(float f) {
    unsigned b = __float_as_uint(f);
    return (b & 0x80000000u) ? ~b : (b | 0x80000000u);
}
__device__ __forceinline__ float funkey(unsigned k) {
    unsigned b = (k & 0x80000000u) ? (k & 0x7fffffffu) : ~k;
    return __uint_as_float(b);
}

// round-to-nearest-even f32 -> bf16 (as uint16 in low bits)
__device__ __forceinline__ unsigned bf16rn(float f) {
    unsigned u = __float_as_uint(f);
    unsigned r = (u >> 16) & 1u;
    return (u + 0x7fffu + r) >> 16;
}

// ---------------------------------------------------------------------------
// Kernel 1: pack pts (AoS float4) and feat = W0[:,3:] @ points stored as bf16
// pairs. Block = 4 waves over the same 64 points; wave w computes outs [8w,8w+8).
// ---------------------------------------------------------------------------
__global__ __launch_bounds__(256) void prep_kernel(
    const float* __restrict__ xyz, const float* __restrict__ points,
    const float* __restrict__ W0, float4* __restrict__ pts4,
    unsigned* __restrict__ featb)
{
    const int tid  = threadIdx.x;
    const int w    = __builtin_amdgcn_readfirstlane(tid >> 6);  // 0..3
    const int lane = tid & 63;
    const int t    = blockIdx.x * 64 + lane;     // point id, 512 blocks
    const int b    = t >> 13;
    const int n    = t & (NP - 1);

    if (w == 0) {
        const float* xb = xyz + (size_t)b * 3 * NP;
        float x = xb[n], y = xb[NP + n], z = xb[2 * NP + n];
        float s = x * x + y * y + z * z;
        pts4[t] = make_float4(x, y, z, s);
    }

    const float* pb = points + (size_t)b * DIN * NP + n;
    float p[DIN];
#pragma unroll
    for (int c = 0; c < DIN; ++c) p[c] = pb[c * NP];

    uint4 outv;
    unsigned* ov = (unsigned*)&outv;
#pragma unroll
    for (int r = 0; r < 4; ++r) {
        int oe = w * 8 + 2 * r;
        float a0 = 0.f, a1 = 0.f;
#pragma unroll
        for (int c = 0; c < DIN; ++c) {
            a0 = fmaf(W0[oe * 35 + 3 + c], p[c], a0);
            a1 = fmaf(W0[(oe + 1) * 35 + 3 + c], p[c], a1);
        }
        ov[r] = bf16rn(a0) | (bf16rn(a1) << 16);
    }
    *(uint4*)(featb + (size_t)t * 16 + w * 4) = outv;
}

// ---------------------------------------------------------------------------
// Kernel 2: exact 16-NN. lane = point, packed query pairs (v_pk_fma_f32).
// 16 waves/block, 64 queries. Each lane owns 8 points in registers, loaded
// ONCE (coalesced dwordx4) and reused in pass 2.
// CRITICAL: the 32-iteration query-pair loops are `#pragma unroll 1` —
// full unroll hoists 32 iterations of LDS reads and blows the 64-VGPR
// budget (LDS 59KB -> 2 blk/CU -> 8 waves/EU -> 64 VGPR), causing the
// 0.5 GB scratch-spill catastrophe measured in r6-r8.
// Pass 1: packed min over 8 pts -> atomicMin into skey[q][lane] (64 classes).
// T[q] = 16th smallest of 64 class minima (>=16 distinct points <= T).
// Pass 2: bit-identical packed recompute, append t<=T to cand[q*81+pos];
// exact (t,idx)-lex top-16; overflow -> exact full scan.
// ---------------------------------------------------------------------------
__global__ __launch_bounds__(1024, 4) void knn_kernel(const float4* __restrict__ pts4,
                                                      int* __restrict__ idxout)
{
    __shared__ float    qx2[64], qy2[64], qz2[64];  // -2*coord per query
    __shared__ unsigned skey[64 * 65];              // 16.6 KB class-min keys
    __shared__ float    sT[64];
    __shared__ int      scnt[64];
    __shared__ float    cand_t[64 * CSTR];          // 20.7 KB
    __shared__ int      cand_i[64 * CSTR];          // 20.7 KB

    const int tid  = threadIdx.x;
    const int w    = __builtin_amdgcn_readfirstlane(tid >> 6);
    const int lane = tid & 63;
    const int blk  = blockIdx.x;           // 512 blocks
    const int b    = blk >> 7;
    const int n0   = (blk & 127) << 6;
    const int bn0  = b * NP;
    const float4* P = pts4 + bn0;

    for (int i = tid; i < 64 * 65; i += 1024) skey[i] = 0xFFFFFFFFu;
    if (tid < 64) {
        float4 q4 = P[n0 + tid];
        qx2[tid] = -2.f * q4.x; qy2[tid] = -2.f * q4.y; qz2[tid] = -2.f * q4.z;
        scnt[tid] = 0;
    }
    __syncthreads();

    // ---- load my 8 points once (coalesced dwordx4, register-resident) ----
    const int base = w * SEG;
    float4 pt[PPL];
#pragma unroll
    for (int i = 0; i < PPL; ++i) pt[i] = P[base + i * 64 + lane];

    // ---- pass 1: per query-pair packed minima over my 8 points ----
#pragma unroll 1
    for (int p = 0; p < 32; ++p) {
        v2f cx = *(const v2f*)&qx2[2 * p];
        v2f cy = *(const v2f*)&qy2[2 * p];
        v2f cz = *(const v2f*)&qz2[2 * p];
        v2f m2 = {1e30f, 1e30f};
#pragma unroll
        for (int i = 0; i < PPL; ++i) {
            v2f px = {pt[i].x, pt[i].x};
            v2f py = {pt[i].y, pt[i].y};
            v2f pz = {pt[i].z, pt[i].z};
            v2f pw = {pt[i].w, pt[i].w};
            v2f t = __builtin_elementwise_fma(cx, px,
                     __builtin_elementwise_fma(cy, py,
                      __builtin_elementwise_fma(cz, pz, pw)));
            m2 = __builtin_elementwise_min(m2, t);
        }
        atomicMin(&skey[(2 * p) * 65 + lane], fkey(m2.x));
        atomicMin(&skey[(2 * p + 1) * 65 + lane], fkey(m2.y));
    }
    __syncthreads();

    // ---- threshold: 16th smallest of the 64 class minima (thread = query) ----
    if (tid < 64) {
        unsigned t16[16];
#pragma unroll
        for (int i = 0; i < 16; ++i) t16[i] = 0xFFFFFFFFu;
        for (int c = 0; c < 64; ++c) {
            unsigned d = skey[tid * 65 + c];
            if (d < t16[15]) {
                t16[15] = d;
#pragma unroll
                for (int i = 15; i > 0; --i) {
                    unsigned a = t16[i - 1], cc = t16[i];
                    t16[i - 1] = umin_(a, cc);
                    t16[i]     = umax_(a, cc);
                }
            }
        }
        sT[tid] = funkey(t16[15]);
    }
    __syncthreads();

    // ---- pass 2: bit-identical packed recompute, append candidates ----
#pragma unroll 1
    for (int p = 0; p < 32; ++p) {
        float T0 = sT[2 * p], T1 = sT[2 * p + 1];
        v2f cx = *(const v2f*)&qx2[2 * p];
        v2f cy = *(const v2f*)&qy2[2 * p];
        v2f cz = *(const v2f*)&qz2[2 * p];
#pragma unroll
        for (int i = 0; i < PPL; ++i) {
            v2f px = {pt[i].x, pt[i].x};
            v2f py = {pt[i].y, pt[i].y};
            v2f pz = {pt[i].z, pt[i].z};
            v2f pw = {pt[i].w, pt[i].w};
            v2f t = __builtin_elementwise_fma(cx, px,
                     __builtin_elementwise_fma(cy, py,
                      __builtin_elementwise_fma(cz, pz, pw)));
            int j = base + i * 64 + lane;
            if (t.x <= T0) {
                int pos = atomicAdd(&scnt[2 * p], 1);
                if (pos < CAP) { cand_t[(2 * p) * CSTR + pos] = t.x; cand_i[(2 * p) * CSTR + pos] = j; }
            }
            if (t.y <= T1) {
                int pos = atomicAdd(&scnt[2 * p + 1], 1);
                if (pos < CAP) { cand_t[(2 * p + 1) * CSTR + pos] = t.y; cand_i[(2 * p + 1) * CSTR + pos] = j; }
            }
        }
    }
    __syncthreads();

    // ---- exact selection among candidates (thread = query) ----
    if (tid < 64) {
        int cnt = scnt[tid];
        int* outp = idxout + ((bn0 + n0 + tid) << 4);
        float bd[16]; int bi[16];
#pragma unroll
        for (int i = 0; i < 16; ++i) { bd[i] = 3e38f; bi[i] = 0; }
        if (cnt <= CAP) {
            for (int pos = 0; pos < cnt; ++pos) {
                float d = cand_t[tid * CSTR + pos];
                int   j = cand_i[tid * CSTR + pos];
                if ((d < bd[15]) || (d == bd[15] && j < bi[15])) {
                    bd[15] = d; bi[15] = j;
#pragma unroll
                    for (int i = 15; i > 0; --i) {
                        bool sw = (bd[i] < bd[i - 1]) || (bd[i] == bd[i - 1] && bi[i] < bi[i - 1]);
                        float td = bd[i - 1]; int tj = bi[i - 1];
                        bd[i - 1] = sw ? bd[i] : td;  bi[i - 1] = sw ? bi[i] : tj;
                        bd[i]     = sw ? td : bd[i];  bi[i]     = sw ? tj : bi[i];
                    }
                }
            }
        } else {
            // overflow fallback (exact, never expected): identical metric form
            float cx = qx2[tid], cy = qy2[tid], cz = qz2[tid];
            for (int j = 0; j < NP; ++j) {
                float4 p = P[j];
                float d = fmaf(cx, p.x, fmaf(cy, p.y, fmaf(cz, p.z, p.w)));
                if ((d < bd[15]) || (d == bd[15] && j < bi[15])) {
                    bd[15] = d; bi[15] = j;
#pragma unroll
                    for (int i = 15; i > 0; --i) {
                        bool sw = (bd[i] < bd[i - 1]) || (bd[i] == bd[i - 1] && bi[i] < bi[i - 1]);
                        float td = bd[i - 1]; int tj = bi[i - 1];
                        bd[i - 1] = sw ? bd[i] : td;  bi[i - 1] = sw ? bi[i] : tj;
                        bd[i]     = sw ? td : bd[i];  bi[i]     = sw ? tj : bi[i];
                    }
                }
            }
        }
#pragma unroll
        for (int i = 0; i < 16; ++i) outp[i] = bi[i];
    }
}

// ---------------------------------------------------------------------------
// Kernel 3: gather + conv0/1/2 + max over K. One thread per (n,k) column,
// 256-thread blocks (16 n x 16 k), 2048 blocks. feat gathered as bf16.
// k-max via shfl_xor width 16.
// ---------------------------------------------------------------------------
__global__ __launch_bounds__(256, 4) void conv_kernel(
    const float4* __restrict__ pts4, const unsigned* __restrict__ featb,
    const int* __restrict__ idx,
    const float* __restrict__ W0, const float* __restrict__ W1, const float* __restrict__ W2,
    float* __restrict__ out)
{
    __shared__ float so[M2][17];
    const int tid = threadIdx.x;
    const int k   = tid & 15;
    const int nl  = tid >> 4;              // 0..15
    const int blk = blockIdx.x;            // 2048 blocks
    const int b   = blk >> 9;              // 512 blocks per batch
    const int n0  = (blk & 511) << 4;
    const int n   = n0 + nl;
    const int bn  = b * NP + n;
    const int j   = idx[(bn << 4) + k];
    const int bj  = b * NP + j;

    const float4 pc = pts4[bn];
    const float4 pj = pts4[bj];
    const float rx = pj.x - pc.x, ry = pj.y - pc.y, rz = pj.z - pc.z;

    const uint4* fj = (const uint4*)(featb + (size_t)bj * 16);

    float x0[M0];
#pragma unroll
    for (int g = 0; g < 4; ++g) {
        uint4 u = fj[g];
        const unsigned* uv = (const unsigned*)&u;
#pragma unroll
        for (int r = 0; r < 4; ++r) {
            int o = g * 8 + 2 * r;
            float fe  = __uint_as_float(uv[r] << 16);
            float fo_ = __uint_as_float(uv[r] & 0xffff0000u);
            x0[o]     = lrelu(fmaf(W0[o * 35], rx, fmaf(W0[o * 35 + 1], ry, fmaf(W0[o * 35 + 2], rz, fe))));
            x0[o + 1] = lrelu(fmaf(W0[(o + 1) * 35], rx, fmaf(W0[(o + 1) * 35 + 1], ry, fmaf(W0[(o + 1) * 35 + 2], rz, fo_))));
        }
    }

    float x1[M1];
#pragma unroll
    for (int o = 0; o < M1; ++o) {
        float acc = 0.f;
#pragma unroll
        for (int c = 0; c < M0; ++c) acc = fmaf(W1[o * 32 + c], x0[c], acc);
        x1[o] = lrelu(acc);
    }

#pragma unroll
    for (int o = 0; o < M2; ++o) {
        float acc = 0.f;
#pragma unroll
        for (int c = 0; c < M1; ++c) acc = fmaf(W2[o * 32 + c], x1[c], acc);
        float v = lrelu(acc);
        v = fmaxf(v, __shfl_xor(v, 1, 16));
        v = fmaxf(v, __shfl_xor(v, 2, 16));
        v = fmaxf(v, __shfl_xor(v, 4, 16));
        v = fmaxf(v, __shfl_xor(v, 8, 16));
        if (k == (o & 15)) so[o][nl] = v;
    }
    __syncthreads();
    {
        int o = tid >> 2;                 // 0..63
        int col = (tid & 3) << 2;         // 0,4,8,12
        float4 v = make_float4(so[o][col], so[o][col + 1], so[o][col + 2], so[o][col + 3]);
        *(float4*)(out + ((size_t)(b * M2 + o)) * NP + n0 + col) = v;
    }
}

// ---------------------------------------------------------------------------
extern "C" void kernel_launch(void* const* d_in, const int* in_sizes, int n_in,
                              void* d_out, int out_size, void* d_ws, size_t ws_size,
                              hipStream_t stream)
{
    const float* xyz    = (const float*)d_in[0];
    const float* points = (const float*)d_in[1];
    const float* W0     = (const float*)d_in[2];
    const float* W1     = (const float*)d_in[3];
    const float* W2     = (const float*)d_in[4];
    float* out = (float*)d_out;

    char* ws = (char*)d_ws;
    float4*   pts4  = (float4*)ws;                       // 512 KB
    unsigned* featb = (unsigned*)(ws + 0x100000);        // 2 MB
    int*      idx   = (int*)(ws + 0x300000);             // 2 MB

    prep_kernel<<<BB * NP / 64, 256,  0, stream>>>(xyz, points, W0, pts4, featb);
    knn_kernel <<<BB * NP / 64, 1024, 0, stream>>>(pts4, idx);
    conv_kernel<<<BB * NP / 16, 256,  0, stream>>>(pts4, featb, idx, W0, W1, W2, out);
}

// Round 10
// 237.496 us; speedup vs baseline: 3.0755x; 1.1462x over previous
//
#include <hip/hip_runtime.h>

#define NP   8192
#define BB   4
#define DIN  32
#define M0   32
#define M1   32
#define M2   64
#define CAP  80
#define CSTR 81            // candidate row stride (odd -> conflict-free)
#define KWV  16            // waves per knn block
#define SEG  (NP / KWV)    // 512 points per wave

typedef float v2f __attribute__((ext_vector_type(2)));

__device__ __forceinline__ float lrelu(float x) { return fmaxf(x, 0.1f * x); }
__device__ __forceinline__ unsigned umin_(unsigned a, unsigned b) { return a < b ? a : b; }
__device__ __forceinline__ unsigned umax_(unsigned a, unsigned b) { return a > b ? a : b; }

// monotonic float->uint key (total order incl. negatives)
__device__ __forceinline__ unsigned fkey(float f) {
    unsigned b = __float_as_uint(f);
    return (b & 0x80000000u) ? ~b : (b | 0x80000000u);
}
__device__ __forceinline__ float funkey(unsigned k) {
    unsigned b = (k & 0x80000000u) ? (k & 0x7fffffffu) : ~k;
    return __uint_as_float(b);
}

// round-to-nearest-even f32 -> bf16 (as uint16 in low bits)
__device__ __forceinline__ unsigned bf16rn(float f) {
    unsigned u = __float_as_uint(f);
    unsigned r = (u >> 16) & 1u;
    return (u + 0x7fffu + r) >> 16;
}

// ---------------------------------------------------------------------------
// Kernel 1: pack pts (AoS float4) and feat = W0[:,3:] @ points stored as bf16
// pairs. Block = 4 waves over the same 64 points; wave w computes outs [8w,8w+8).
// ---------------------------------------------------------------------------
__global__ __launch_bounds__(256) void prep_kernel(
    const float* __restrict__ xyz, const float* __restrict__ points,
    const float* __restrict__ W0, float4* __restrict__ pts4,
    unsigned* __restrict__ featb)
{
    const int tid  = threadIdx.x;
    const int w    = __builtin_amdgcn_readfirstlane(tid >> 6);  // 0..3
    const int lane = tid & 63;
    const int t    = blockIdx.x * 64 + lane;     // point id, 512 blocks
    const int b    = t >> 13;
    const int n    = t & (NP - 1);

    if (w == 0) {
        const float* xb = xyz + (size_t)b * 3 * NP;
        float x = xb[n], y = xb[NP + n], z = xb[2 * NP + n];
        float s = x * x + y * y + z * z;
        pts4[t] = make_float4(x, y, z, s);
    }

    const float* pb = points + (size_t)b * DIN * NP + n;
    float p[DIN];
#pragma unroll
    for (int c = 0; c < DIN; ++c) p[c] = pb[c * NP];

    uint4 outv;
    unsigned* ov = (unsigned*)&outv;
#pragma unroll
    for (int r = 0; r < 4; ++r) {
        int oe = w * 8 + 2 * r;
        float a0 = 0.f, a1 = 0.f;
#pragma unroll
        for (int c = 0; c < DIN; ++c) {
            a0 = fmaf(W0[oe * 35 + 3 + c], p[c], a0);
            a1 = fmaf(W0[(oe + 1) * 35 + 3 + c], p[c], a1);
        }
        ov[r] = bf16rn(a0) | (bf16rn(a1) << 16);
    }
    *(uint4*)(featb + (size_t)t * 16 + w * 4) = outv;
}

// ---------------------------------------------------------------------------
// Kernel 2: exact 16-NN. lane = point, POINTS packed in v2f pairs (loop-
// invariant, packed once -> no per-iteration broadcast movs, the r9 overhead).
// 16 waves/block, 64 queries. Each lane owns 8 points (4 pairs) in registers.
// Per query: one ds_read_b128 of qc[q] = (-2qx,-2qy,-2qz,T); 12 pk_fma +
// 4 pk_min cover all 8 points.
// Pass 1: mn(lane,q) -> atomicMin skey[q][lane] (64 classes/query).
// T[q] = 16th smallest of 64 class minima -> stored into qc[q].w.
// Pass 2: identical t computation (bit-identical); whole-lane skip if
// min8 > T; appends to cand[q*81+pos]; exact (t,idx)-lex top-16; overflow
// -> exact full scan (same fma association -> bit-identical).
// The 64-iteration query loops are `#pragma unroll 1`: full unroll blows the
// 64-VGPR budget (32-wave/CU cap) -> 0.5 GB scratch spill (r8).
// ---------------------------------------------------------------------------
__global__ __launch_bounds__(1024, 4) void knn_kernel(const float4* __restrict__ pts4,
                                                      int* __restrict__ idxout)
{
    __shared__ float4   qc[64];                     // (-2x,-2y,-2z,T): 1 KB
    __shared__ unsigned skey[64 * 65];              // 16.6 KB class-min keys
    __shared__ int      scnt[64];
    __shared__ float    cand_t[64 * CSTR];          // 20.7 KB
    __shared__ int      cand_i[64 * CSTR];          // 20.7 KB

    const int tid  = threadIdx.x;
    const int w    = __builtin_amdgcn_readfirstlane(tid >> 6);
    const int lane = tid & 63;
    const int blk  = blockIdx.x;           // 512 blocks
    const int b    = blk >> 7;
    const int n0   = (blk & 127) << 6;
    const int bn0  = b * NP;
    const float4* P = pts4 + bn0;

    for (int i = tid; i < 64 * 65; i += 1024) skey[i] = 0xFFFFFFFFu;
    if (tid < 64) {
        float4 q4 = P[n0 + tid];
        qc[tid] = make_float4(-2.f * q4.x, -2.f * q4.y, -2.f * q4.z, 0.f);
        scnt[tid] = 0;
    }
    __syncthreads();

    // ---- load + pack my 8 points into pairs (once; in halves for pressure) ----
    const int base = w * SEG;
    v2f ptx[4], pty[4], ptz[4], ptw[4];
#pragma unroll
    for (int j = 0; j < 4; ++j) {
        float4 a  = P[base + (2 * j) * 64 + lane];
        float4 b2 = P[base + (2 * j + 1) * 64 + lane];
        ptx[j] = (v2f){a.x, b2.x};  pty[j] = (v2f){a.y, b2.y};
        ptz[j] = (v2f){a.z, b2.z};  ptw[j] = (v2f){a.w, b2.w};
    }

    // ---- pass 1: per-query min over my 8 points -> class merge ----
#pragma unroll 1
    for (int q = 0; q < 64; ++q) {
        float4 c = qc[q];                  // ds_read_b128
        v2f cx = {c.x, c.x}, cy = {c.y, c.y}, cz = {c.z, c.z};
        v2f m2 = {1e30f, 1e30f};
#pragma unroll
        for (int j = 0; j < 4; ++j) {
            v2f t = __builtin_elementwise_fma(cx, ptx[j],
                     __builtin_elementwise_fma(cy, pty[j],
                      __builtin_elementwise_fma(cz, ptz[j], ptw[j])));
            m2 = __builtin_elementwise_min(m2, t);
        }
        float mn = fminf(m2.x, m2.y);
        atomicMin(&skey[q * 65 + lane], fkey(mn));
    }
    __syncthreads();

    // ---- threshold: 16th smallest of the 64 class minima -> qc[q].w ----
    if (tid < 64) {
        unsigned t16[16];
#pragma unroll
        for (int i = 0; i < 16; ++i) t16[i] = 0xFFFFFFFFu;
        for (int c = 0; c < 64; ++c) {
            unsigned d = skey[tid * 65 + c];
            if (d < t16[15]) {
                t16[15] = d;
#pragma unroll
                for (int i = 15; i > 0; --i) {
                    unsigned a = t16[i - 1], cc = t16[i];
                    t16[i - 1] = umin_(a, cc);
                    t16[i]     = umax_(a, cc);
                }
            }
        }
        qc[tid].w = funkey(t16[15]);
    }
    __syncthreads();

    // ---- pass 2: bit-identical recompute, whole-lane skip, append ----
#pragma unroll 1
    for (int q = 0; q < 64; ++q) {
        float4 c = qc[q];                  // cx,cy,cz,T in one b128
        v2f cx = {c.x, c.x}, cy = {c.y, c.y}, cz = {c.z, c.z};
        v2f t0 = __builtin_elementwise_fma(cx, ptx[0],
                  __builtin_elementwise_fma(cy, pty[0],
                   __builtin_elementwise_fma(cz, ptz[0], ptw[0])));
        v2f t1 = __builtin_elementwise_fma(cx, ptx[1],
                  __builtin_elementwise_fma(cy, pty[1],
                   __builtin_elementwise_fma(cz, ptz[1], ptw[1])));
        v2f t2 = __builtin_elementwise_fma(cx, ptx[2],
                  __builtin_elementwise_fma(cy, pty[2],
                   __builtin_elementwise_fma(cz, ptz[2], ptw[2])));
        v2f t3 = __builtin_elementwise_fma(cx, ptx[3],
                  __builtin_elementwise_fma(cy, pty[3],
                   __builtin_elementwise_fma(cz, ptz[3], ptw[3])));
        v2f mm = __builtin_elementwise_min(
                   __builtin_elementwise_min(t0, t1),
                   __builtin_elementwise_min(t2, t3));
        if (fminf(mm.x, mm.y) <= c.w) {    // rare (~2-3% of lanes per q)
            float tv[8] = {t0.x, t0.y, t1.x, t1.y, t2.x, t2.y, t3.x, t3.y};
#pragma unroll
            for (int i = 0; i < 8; ++i) {
                if (tv[i] <= c.w) {
                    int pos = atomicAdd(&scnt[q], 1);
                    if (pos < CAP) {
                        cand_t[q * CSTR + pos] = tv[i];
                        cand_i[q * CSTR + pos] = base + i * 64 + lane;
                    }
                }
            }
        }
    }
    __syncthreads();

    // ---- exact selection among candidates (thread = query) ----
    if (tid < 64) {
        int cnt = scnt[tid];
        int* outp = idxout + ((bn0 + n0 + tid) << 4);
        float bd[16]; int bi[16];
#pragma unroll
        for (int i = 0; i < 16; ++i) { bd[i] = 3e38f; bi[i] = 0; }
        if (cnt <= CAP) {
            for (int pos = 0; pos < cnt; ++pos) {
                float d = cand_t[tid * CSTR + pos];
                int   j = cand_i[tid * CSTR + pos];
                if ((d < bd[15]) || (d == bd[15] && j < bi[15])) {
                    bd[15] = d; bi[15] = j;
#pragma unroll
                    for (int i = 15; i > 0; --i) {
                        bool sw = (bd[i] < bd[i - 1]) || (bd[i] == bd[i - 1] && bi[i] < bi[i - 1]);
                        float td = bd[i - 1]; int tj = bi[i - 1];
                        bd[i - 1] = sw ? bd[i] : td;  bi[i - 1] = sw ? bi[i] : tj;
                        bd[i]     = sw ? td : bd[i];  bi[i]     = sw ? tj : bi[i];
                    }
                }
            }
        } else {
            // overflow fallback (exact, never expected): identical association
            float cx = qc[tid].x, cy = qc[tid].y, cz = qc[tid].z;
            for (int j = 0; j < NP; ++j) {
                float4 p = P[j];
                float d = fmaf(cx, p.x, fmaf(cy, p.y, fmaf(cz, p.z, p.w)));
                if ((d < bd[15]) || (d == bd[15] && j < bi[15])) {
                    bd[15] = d; bi[15] = j;
#pragma unroll
                    for (int i = 15; i > 0; --i) {
                        bool sw = (bd[i] < bd[i - 1]) || (bd[i] == bd[i - 1] && bi[i] < bi[i - 1]);
                        float td = bd[i - 1]; int tj = bi[i - 1];
                        bd[i - 1] = sw ? bd[i] : td;  bi[i - 1] = sw ? bi[i] : tj;
                        bd[i]     = sw ? td : bd[i];  bi[i]     = sw ? tj : bi[i];
                    }
                }
            }
        }
#pragma unroll
        for (int i = 0; i < 16; ++i) outp[i] = bi[i];
    }
}

// ---------------------------------------------------------------------------
// Kernel 3: gather + conv0/1/2 + max over K. One thread per (n,k) column,
// 256-thread blocks (16 n x 16 k), 2048 blocks. feat gathered as bf16.
// k-max via shfl_xor width 16.
// ---------------------------------------------------------------------------
__global__ __launch_bounds__(256, 4) void conv_kernel(
    const float4* __restrict__ pts4, const unsigned* __restrict__ featb,
    const int* __restrict__ idx,
    const float* __restrict__ W0, const float* __restrict__ W1, const float* __restrict__ W2,
    float* __restrict__ out)
{
    __shared__ float so[M2][17];
    const int tid = threadIdx.x;
    const int k   = tid & 15;
    const int nl  = tid >> 4;              // 0..15
    const int blk = blockIdx.x;            // 2048 blocks
    const int b   = blk >> 9;              // 512 blocks per batch
    const int n0  = (blk & 511) << 4;
    const int n   = n0 + nl;
    const int bn  = b * NP + n;
    const int j   = idx[(bn << 4) + k];
    const int bj  = b * NP + j;

    const float4 pc = pts4[bn];
    const float4 pj = pts4[bj];
    const float rx = pj.x - pc.x, ry = pj.y - pc.y, rz = pj.z - pc.z;

    const uint4* fj = (const uint4*)(featb + (size_t)bj * 16);

    float x0[M0];
#pragma unroll
    for (int g = 0; g < 4; ++g) {
        uint4 u = fj[g];
        const unsigned* uv = (const unsigned*)&u;
#pragma unroll
        for (int r = 0; r < 4; ++r) {
            int o = g * 8 + 2 * r;
            float fe  = __uint_as_float(uv[r] << 16);
            float fo_ = __uint_as_float(uv[r] & 0xffff0000u);
            x0[o]     = lrelu(fmaf(W0[o * 35], rx, fmaf(W0[o * 35 + 1], ry, fmaf(W0[o * 35 + 2], rz, fe))));
            x0[o + 1] = lrelu(fmaf(W0[(o + 1) * 35], rx, fmaf(W0[(o + 1) * 35 + 1], ry, fmaf(W0[(o + 1) * 35 + 2], rz, fo_))));
        }
    }

    float x1[M1];
#pragma unroll
    for (int o = 0; o < M1; ++o) {
        float acc = 0.f;
#pragma unroll
        for (int c = 0; c < M0; ++c) acc = fmaf(W1[o * 32 + c], x0[c], acc);
        x1[o] = lrelu(acc);
    }

#pragma unroll
    for (int o = 0; o < M2; ++o) {
        float acc = 0.f;
#pragma unroll
        for (int c = 0; c < M1; ++c) acc = fmaf(W2[o * 32 + c], x1[c], acc);
        float v = lrelu(acc);
        v = fmaxf(v, __shfl_xor(v, 1, 16));
        v = fmaxf(v, __shfl_xor(v, 2, 16));
        v = fmaxf(v, __shfl_xor(v, 4, 16));
        v = fmaxf(v, __shfl_xor(v, 8, 16));
        if (k == (o & 15)) so[o][nl] = v;
    }
    __syncthreads();
    {
        int o = tid >> 2;                 // 0..63
        int col = (tid & 3) << 2;         // 0,4,8,12
        float4 v = make_float4(so[o][col], so[o][col + 1], so[o][col + 2], so[o][col + 3]);
        *(float4*)(out + ((size_t)(b * M2 + o)) * NP + n0 + col) = v;
    }
}

// ---------------------------------------------------------------------------
extern "C" void kernel_launch(void* const* d_in, const int* in_sizes, int n_in,
                              void* d_out, int out_size, void* d_ws, size_t ws_size,
                              hipStream_t stream)
{
    const float* xyz    = (const float*)d_in[0];
    const float* points = (const float*)d_in[1];
    const float* W0     = (const float*)d_in[2];
    const float* W1     = (const float*)d_in[3];
    const float* W2     = (const float*)d_in[4];
    float* out = (float*)d_out;

    char* ws = (char*)d_ws;
    float4*   pts4  = (float4*)ws;                       // 512 KB
    unsigned* featb = (unsigned*)(ws + 0x100000);        // 2 MB
    int*      idx   = (int*)(ws + 0x300000);             // 2 MB

    prep_kernel<<<BB * NP / 64, 256,  0, stream>>>(xyz, points, W0, pts4, featb);
    knn_kernel <<<BB * NP / 64, 1024, 0, stream>>>(pts4, idx);
    conv_kernel<<<BB * NP / 16, 256,  0, stream>>>(pts4, featb, idx, W0, W1, W2, out);
}

// Round 11
// 232.950 us; speedup vs baseline: 3.1355x; 1.0195x over previous
//
#include <hip/hip_runtime.h>

#define NP   8192
#define BB   4
#define DIN  32
#define M0   32
#define M1   32
#define M2   64
#define CAP  80
#define CSTR 81            // candidate row stride (odd -> conflict-free)
#define KWV  16            // waves per knn block
#define SEG  (NP / KWV)    // 512 points per wave

typedef float v2f __attribute__((ext_vector_type(2)));

__device__ __forceinline__ float lrelu(float x) { return fmaxf(x, 0.1f * x); }
__device__ __forceinline__ unsigned umin_(unsigned a, unsigned b) { return a < b ? a : b; }
__device__ __forceinline__ unsigned umax_(unsigned a, unsigned b) { return a > b ? a : b; }

// monotonic float->uint key (total order incl. negatives)
__device__ __forceinline__ unsigned fkey(float f) {
    unsigned b = __float_as_uint(f);
    return (b & 0x80000000u) ? ~b : (b | 0x80000000u);
}
__device__ __forceinline__ float funkey(unsigned k) {
    unsigned b = (k & 0x80000000u) ? (k & 0x7fffffffu) : ~k;
    return __uint_as_float(b);
}

// round-to-nearest-even f32 -> bf16 (as uint16 in low bits)
__device__ __forceinline__ unsigned bf16rn(float f) {
    unsigned u = __float_as_uint(f);
    unsigned r = (u >> 16) & 1u;
    return (u + 0x7fffu + r) >> 16;
}

// ---------------------------------------------------------------------------
// Kernel 1: pack pts (AoS float4) and feat = W0[:,3:] @ points stored as bf16
// pairs. Block = 4 waves over the same 64 points; wave w computes outs [8w,8w+8).
// ---------------------------------------------------------------------------
__global__ __launch_bounds__(256) void prep_kernel(
    const float* __restrict__ xyz, const float* __restrict__ points,
    const float* __restrict__ W0, float4* __restrict__ pts4,
    unsigned* __restrict__ featb)
{
    const int tid  = threadIdx.x;
    const int w    = __builtin_amdgcn_readfirstlane(tid >> 6);  // 0..3
    const int lane = tid & 63;
    const int t    = blockIdx.x * 64 + lane;     // point id, 512 blocks
    const int b    = t >> 13;
    const int n    = t & (NP - 1);

    if (w == 0) {
        const float* xb = xyz + (size_t)b * 3 * NP;
        float x = xb[n], y = xb[NP + n], z = xb[2 * NP + n];
        float s = x * x + y * y + z * z;
        pts4[t] = make_float4(x, y, z, s);
    }

    const float* pb = points + (size_t)b * DIN * NP + n;
    float p[DIN];
#pragma unroll
    for (int c = 0; c < DIN; ++c) p[c] = pb[c * NP];

    uint4 outv;
    unsigned* ov = (unsigned*)&outv;
#pragma unroll
    for (int r = 0; r < 4; ++r) {
        int oe = w * 8 + 2 * r;
        float a0 = 0.f, a1 = 0.f;
#pragma unroll
        for (int c = 0; c < DIN; ++c) {
            a0 = fmaf(W0[oe * 35 + 3 + c], p[c], a0);
            a1 = fmaf(W0[(oe + 1) * 35 + 3 + c], p[c], a1);
        }
        ov[r] = bf16rn(a0) | (bf16rn(a1) << 16);
    }
    *(uint4*)(featb + (size_t)t * 16 + w * 4) = outv;
}

// ---------------------------------------------------------------------------
// Kernel 2: exact 16-NN. lane = point; points packed in v2f pairs ONCE;
// query coefficients stored PRE-DUPLICATED in LDS (qcp[q] = [x2,x2][y2,y2]
// [z2,z2][T,T], 32B/q) so both passes need ZERO broadcast movs (r10's 25%
// overhead). 16 waves/block, 64 queries; each lane owns 8 points (4 pairs).
// Pass 1: min over 8 pts -> atomicMin skey[q][lane] (64 classes/query).
// T[q] = 16th smallest of 64 class minima -> written into qcp[q][3].
// Pass 2: bit-identical recompute; per-PAIR precheck (32% wave-prob vs 79%
// for whole-8) -> append to cand[q*81+pos]; exact (t,idx)-lex top-16;
// overflow -> exact full scan (identical fma association).
// Query loops are `#pragma unroll 1`: full unroll blows the 64-VGPR budget
// (32-wave/CU cap) -> 0.5 GB scratch spill (r8).
// ---------------------------------------------------------------------------
__global__ __launch_bounds__(1024, 4) void knn_kernel(const float4* __restrict__ pts4,
                                                      int* __restrict__ idxout)
{
    __shared__ v2f      qcp[64][4];                 // pre-duplicated coeffs: 2 KB
    __shared__ unsigned skey[64 * 65];              // 16.6 KB class-min keys
    __shared__ int      scnt[64];
    __shared__ float    cand_t[64 * CSTR];          // 20.7 KB
    __shared__ int      cand_i[64 * CSTR];          // 20.7 KB

    const int tid  = threadIdx.x;
    const int w    = __builtin_amdgcn_readfirstlane(tid >> 6);
    const int lane = tid & 63;
    const int blk  = blockIdx.x;           // 512 blocks
    const int b    = blk >> 7;
    const int n0   = (blk & 127) << 6;
    const int bn0  = b * NP;
    const float4* P = pts4 + bn0;

    for (int i = tid; i < 64 * 65; i += 1024) skey[i] = 0xFFFFFFFFu;
    if (tid < 64) {
        float4 q4 = P[n0 + tid];
        qcp[tid][0] = (v2f){-2.f * q4.x, -2.f * q4.x};
        qcp[tid][1] = (v2f){-2.f * q4.y, -2.f * q4.y};
        qcp[tid][2] = (v2f){-2.f * q4.z, -2.f * q4.z};
        qcp[tid][3] = (v2f){0.f, 0.f};
        scnt[tid] = 0;
    }
    __syncthreads();

    // ---- load + pack my 8 points into pairs (once, register-resident) ----
    const int base = w * SEG;
    v2f ptx[4], pty[4], ptz[4], ptw[4];
#pragma unroll
    for (int j = 0; j < 4; ++j) {
        float4 a  = P[base + (2 * j) * 64 + lane];
        float4 b2 = P[base + (2 * j + 1) * 64 + lane];
        ptx[j] = (v2f){a.x, b2.x};  pty[j] = (v2f){a.y, b2.y};
        ptz[j] = (v2f){a.z, b2.z};  ptw[j] = (v2f){a.w, b2.w};
    }

    // ---- pass 1: per-query min over my 8 points -> class merge ----
#pragma unroll 1
    for (int q = 0; q < 64; ++q) {
        v2f cx = qcp[q][0], cy = qcp[q][1], cz = qcp[q][2];   // pre-duplicated
        v2f m2 = {1e30f, 1e30f};
#pragma unroll
        for (int j = 0; j < 4; ++j) {
            v2f t = __builtin_elementwise_fma(cx, ptx[j],
                     __builtin_elementwise_fma(cy, pty[j],
                      __builtin_elementwise_fma(cz, ptz[j], ptw[j])));
            m2 = __builtin_elementwise_min(m2, t);
        }
        float mn = fminf(m2.x, m2.y);
        atomicMin(&skey[q * 65 + lane], fkey(mn));
    }
    __syncthreads();

    // ---- threshold: 16th smallest of the 64 class minima -> qcp[q][3] ----
    if (tid < 64) {
        unsigned t16[16];
#pragma unroll
        for (int i = 0; i < 16; ++i) t16[i] = 0xFFFFFFFFu;
        for (int c = 0; c < 64; ++c) {
            unsigned d = skey[tid * 65 + c];
            if (d < t16[15]) {
                t16[15] = d;
#pragma unroll
                for (int i = 15; i > 0; --i) {
                    unsigned a = t16[i - 1], cc = t16[i];
                    t16[i - 1] = umin_(a, cc);
                    t16[i]     = umax_(a, cc);
                }
            }
        }
        float T = funkey(t16[15]);
        qcp[tid][3] = (v2f){T, T};
    }
    __syncthreads();

    // ---- pass 2: bit-identical recompute, per-pair precheck, append ----
#pragma unroll 1
    for (int q = 0; q < 64; ++q) {
        v2f cx = qcp[q][0], cy = qcp[q][1], cz = qcp[q][2];
        float T = qcp[q][3].x;
#pragma unroll
        for (int j = 0; j < 4; ++j) {
            v2f t = __builtin_elementwise_fma(cx, ptx[j],
                     __builtin_elementwise_fma(cy, pty[j],
                      __builtin_elementwise_fma(cz, ptz[j], ptw[j])));
            if (fminf(t.x, t.y) <= T) {          // ~32% wave-prob per pair
                int jb = base + (2 * j) * 64 + lane;
                if (t.x <= T) {
                    int pos = atomicAdd(&scnt[q], 1);
                    if (pos < CAP) { cand_t[q * CSTR + pos] = t.x; cand_i[q * CSTR + pos] = jb; }
                }
                if (t.y <= T) {
                    int pos = atomicAdd(&scnt[q], 1);
                    if (pos < CAP) { cand_t[q * CSTR + pos] = t.y; cand_i[q * CSTR + pos] = jb + 64; }
                }
            }
        }
    }
    __syncthreads();

    // ---- exact selection among candidates (thread = query) ----
    if (tid < 64) {
        int cnt = scnt[tid];
        int* outp = idxout + ((bn0 + n0 + tid) << 4);
        float bd[16]; int bi[16];
#pragma unroll
        for (int i = 0; i < 16; ++i) { bd[i] = 3e38f; bi[i] = 0; }
        if (cnt <= CAP) {
            for (int pos = 0; pos < cnt; ++pos) {
                float d = cand_t[tid * CSTR + pos];
                int   j = cand_i[tid * CSTR + pos];
                if ((d < bd[15]) || (d == bd[15] && j < bi[15])) {
                    bd[15] = d; bi[15] = j;
#pragma unroll
                    for (int i = 15; i > 0; --i) {
                        bool sw = (bd[i] < bd[i - 1]) || (bd[i] == bd[i - 1] && bi[i] < bi[i - 1]);
                        float td = bd[i - 1]; int tj = bi[i - 1];
                        bd[i - 1] = sw ? bd[i] : td;  bi[i - 1] = sw ? bi[i] : tj;
                        bd[i]     = sw ? td : bd[i];  bi[i]     = sw ? tj : bi[i];
                    }
                }
            }
        } else {
            // overflow fallback (exact, never expected): identical association
            float cx = qcp[tid][0].x, cy = qcp[tid][1].x, cz = qcp[tid][2].x;
            for (int j = 0; j < NP; ++j) {
                float4 p = P[j];
                float d = fmaf(cx, p.x, fmaf(cy, p.y, fmaf(cz, p.z, p.w)));
                if ((d < bd[15]) || (d == bd[15] && j < bi[15])) {
                    bd[15] = d; bi[15] = j;
#pragma unroll
                    for (int i = 15; i > 0; --i) {
                        bool sw = (bd[i] < bd[i - 1]) || (bd[i] == bd[i - 1] && bi[i] < bi[i - 1]);
                        float td = bd[i - 1]; int tj = bi[i - 1];
                        bd[i - 1] = sw ? bd[i] : td;  bi[i - 1] = sw ? bi[i] : tj;
                        bd[i]     = sw ? td : bd[i];  bi[i]     = sw ? tj : bi[i];
                    }
                }
            }
        }
#pragma unroll
        for (int i = 0; i < 16; ++i) outp[i] = bi[i];
    }
}

// ---------------------------------------------------------------------------
// Kernel 3: gather + conv0/1/2 + max over K. One thread per (n,k) column,
// 256-thread blocks (16 n x 16 k), 2048 blocks. feat gathered as bf16.
// k-max via shfl_xor width 16. (Unchanged from r10 — awaiting its first
// counter capture once knn drops below it.)
// ---------------------------------------------------------------------------
__global__ __launch_bounds__(256, 4) void conv_kernel(
    const float4* __restrict__ pts4, const unsigned* __restrict__ featb,
    const int* __restrict__ idx,
    const float* __restrict__ W0, const float* __restrict__ W1, const float* __restrict__ W2,
    float* __restrict__ out)
{
    __shared__ float so[M2][17];
    const int tid = threadIdx.x;
    const int k   = tid & 15;
    const int nl  = tid >> 4;              // 0..15
    const int blk = blockIdx.x;            // 2048 blocks
    const int b   = blk >> 9;              // 512 blocks per batch
    const int n0  = (blk & 511) << 4;
    const int n   = n0 + nl;
    const int bn  = b * NP + n;
    const int j   = idx[(bn << 4) + k];
    const int bj  = b * NP + j;

    const float4 pc = pts4[bn];
    const float4 pj = pts4[bj];
    const float rx = pj.x - pc.x, ry = pj.y - pc.y, rz = pj.z - pc.z;

    const uint4* fj = (const uint4*)(featb + (size_t)bj * 16);

    float x0[M0];
#pragma unroll
    for (int g = 0; g < 4; ++g) {
        uint4 u = fj[g];
        const unsigned* uv = (const unsigned*)&u;
#pragma unroll
        for (int r = 0; r < 4; ++r) {
            int o = g * 8 + 2 * r;
            float fe  = __uint_as_float(uv[r] << 16);
            float fo_ = __uint_as_float(uv[r] & 0xffff0000u);
            x0[o]     = lrelu(fmaf(W0[o * 35], rx, fmaf(W0[o * 35 + 1], ry, fmaf(W0[o * 35 + 2], rz, fe))));
            x0[o + 1] = lrelu(fmaf(W0[(o + 1) * 35], rx, fmaf(W0[(o + 1) * 35 + 1], ry, fmaf(W0[(o + 1) * 35 + 2], rz, fo_))));
        }
    }

    float x1[M1];
#pragma unroll
    for (int o = 0; o < M1; ++o) {
        float acc = 0.f;
#pragma unroll
        for (int c = 0; c < M0; ++c) acc = fmaf(W1[o * 32 + c], x0[c], acc);
        x1[o] = lrelu(acc);
    }

#pragma unroll
    for (int o = 0; o < M2; ++o) {
        float acc = 0.f;
#pragma unroll
        for (int c = 0; c < M1; ++c) acc = fmaf(W2[o * 32 + c], x1[c], acc);
        float v = lrelu(acc);
        v = fmaxf(v, __shfl_xor(v, 1, 16));
        v = fmaxf(v, __shfl_xor(v, 2, 16));
        v = fmaxf(v, __shfl_xor(v, 4, 16));
        v = fmaxf(v, __shfl_xor(v, 8, 16));
        if (k == (o & 15)) so[o][nl] = v;
    }
    __syncthreads();
    {
        int o = tid >> 2;                 // 0..63
        int col = (tid & 3) << 2;         // 0,4,8,12
        float4 v = make_float4(so[o][col], so[o][col + 1], so[o][col + 2], so[o][col + 3]);
        *(float4*)(out + ((size_t)(b * M2 + o)) * NP + n0 + col) = v;
    }
}

// ---------------------------------------------------------------------------
extern "C" void kernel_launch(void* const* d_in, const int* in_sizes, int n_in,
                              void* d_out, int out_size, void* d_ws, size_t ws_size,
                              hipStream_t stream)
{
    const float* xyz    = (const float*)d_in[0];
    const float* points = (const float*)d_in[1];
    const float* W0     = (const float*)d_in[2];
    const float* W1     = (const float*)d_in[3];
    const float* W2     = (const float*)d_in[4];
    float* out = (float*)d_out;

    char* ws = (char*)d_ws;
    float4*   pts4  = (float4*)ws;                       // 512 KB
    unsigned* featb = (unsigned*)(ws + 0x100000);        // 2 MB
    int*      idx   = (int*)(ws + 0x300000);             // 2 MB

    prep_kernel<<<BB * NP / 64, 256,  0, stream>>>(xyz, points, W0, pts4, featb);
    knn_kernel <<<BB * NP / 64, 1024, 0, stream>>>(pts4, idx);
    conv_kernel<<<BB * NP / 16, 256,  0, stream>>>(pts4, featb, idx, W0, W1, W2, out);
}